// Round 6
// baseline (2026.837 us; speedup 1.0000x reference)
//
#include <hip/hip_runtime.h>
#include <cmath>

// PropConv: K=10 hop gated propagation on a fixed graph + output MLP.
// R6: src-bucketed CSR. Edges partitioned into NB=7 buckets by src>>13
// (8192 nodes = 2MB bf16 state per bucket, fits per-XCD 4MiB L2).
// Hop kernel: bucket loop OUTSIDE, accumulators in registers across buckets;
// all ~1563 blocks co-resident march through buckets in phase -> gathers hit
// L2 instead of the ~7TB/s L3 ceiling that bounded R3/R5. Each edge is
// processed exactly once (unlike R4's column panels). In-degree recovered
// from segment bounds (incnt array eliminated).

#define NNODES 50000
#define NEDGES 1600000
#define DD 128
#define KHOPS 10
#define ALPHA 0.1f
#define NB 7          // src buckets
#define BSH 13        // bucket = src >> 13 (8192 nodes/bucket)

static __device__ __forceinline__ unsigned bf16rne(float x) {
    unsigned u = __float_as_uint(x);
    return (u + 0x7FFFu + ((u >> 16) & 1u)) >> 16;
}
static __device__ __forceinline__ float bf_lo(unsigned w) { return __uint_as_float(w << 16); }
static __device__ __forceinline__ float bf_hi(unsigned w) { return __uint_as_float(w & 0xFFFF0000u); }

// 8-entry gate table: gate MLP has only 8 distinct inputs (etypes).
__global__ void gate_kernel(const float* __restrict__ emb, const float* __restrict__ We1,
                            const float* __restrict__ be1, const float* __restrict__ We2,
                            const float* __restrict__ be2, float* __restrict__ gate) {
    int t = threadIdx.x;
    if (t >= 8) return;
    float acc2 = 0.0f;
    for (int j = 0; j < 32; j++) {
        float a = be1[j];
        for (int k = 0; k < DD; k++) a += emb[t * DD + k] * We1[k * 32 + j];
        float g = 0.5f * a * (1.0f + erff(a * 0.70710678118654752f));  // exact GELU
        acc2 += g * We2[j];
    }
    acc2 += be2[0];
    gate[t] = 1.0f + 1.0f / (1.0f + expf(-acc2));   // 1 + sigmoid
}

// Per-(bucket,dst) histogram: one atomic per edge.
__global__ void deg_kernel(const int* __restrict__ src, const int* __restrict__ dst,
                           int* __restrict__ cnt4, int E) {
    int e = blockIdx.x * blockDim.x + threadIdx.x;
    if (e < E) atomicAdd(&cnt4[(src[e] >> BSH) * NNODES + dst[e]], 1);
}

// Single-block exclusive scan of M counts -> seg_ptr (M+1 entries).
__global__ __launch_bounds__(1024) void scan_kernel(const int* __restrict__ cnt,
                                                    int* __restrict__ seg_ptr, int M, int E) {
    __shared__ int part[1024];
    int t = threadIdx.x;
    int chunk = (M + 1023) / 1024;
    int beg = t * chunk; if (beg > M) beg = M;
    int end = beg + chunk; if (end > M) end = M;
    int s = 0;
    for (int i = beg; i < end; i++) s += cnt[i];
    part[t] = s;
    __syncthreads();
    for (int off = 1; off < 1024; off <<= 1) {
        int v = 0;
        if (t >= off) v = part[t - off];
        __syncthreads();
        if (t >= off) part[t] += v;
        __syncthreads();
    }
    int excl = (t == 0) ? 0 : part[t - 1];
    for (int i = beg; i < end; i++) { seg_ptr[i] = excl; excl += cnt[i]; }
    if (t == 0) seg_ptr[M] = E;
}

// Bucket edges by (src-bucket, dst). 4B payload: src | etype<<16. Builds outcnt.
__global__ void scatter_kernel(const int* __restrict__ src, const int* __restrict__ dst,
                               const int* __restrict__ ef, const int* __restrict__ seg_ptr,
                               int* __restrict__ cursor, int* __restrict__ outcnt,
                               int* __restrict__ epay, int E) {
    int e = blockIdx.x * blockDim.x + threadIdx.x;
    if (e >= E) return;
    int d = dst[e];
    int s = src[e];
    int bi = (s >> BSH) * NNODES + d;
    int pos = seg_ptr[bi] + atomicAdd(&cursor[bi], 1);
    epay[pos] = s | (ef[e] << 16);
    atomicAdd(&outcnt[s], 1);
}

// g0 = bf16(feat * src_norm), row-major [N][128] bf16 (256B rows).
__global__ void scale_kernel(const float* __restrict__ feat, const int* __restrict__ outcnt,
                             unsigned* __restrict__ g0, int N) {
    int i = blockIdx.x * blockDim.x + threadIdx.x;   // one float4-group (4 cols)
    if (i >= N * 32) return;
    int row = i >> 5;
    int oc = outcnt[row]; if (oc < 1) oc = 1;
    float sn = rsqrtf((float)oc);
    float4 v = ((const float4*)feat)[i];
    uint2 o;
    o.x = bf16rne(v.x * sn) | (bf16rne(v.y * sn) << 16);
    o.y = bf16rne(v.z * sn) | (bf16rne(v.w * sn) << 16);
    ((uint2*)g0)[i] = o;
}

#define ACC(gi) { a[gi][0] += c * bf_lo(vv.x); a[gi][1] += c * bf_hi(vv.x); \
                  a[gi][2] += c * bf_lo(vv.y); a[gi][3] += c * bf_hi(vv.y); }

// Half-wave (32 lanes) owns 4 consecutive dst nodes; accumulators live in
// registers across the NB bucket phases. Per bucket, the 4 nodes' edges are
// contiguous in epay -> one merged coalesced payload stream; owner segment
// resolved by a wave-uniform 4-way switch. Gathers (8B bf16/lane) hit the
// L2-resident 2MB bucket. x8 unroll -> 8 gathers in flight.
__global__ __launch_bounds__(256) void hop_kernel(const unsigned* __restrict__ g_in,
                                                  const float* __restrict__ feat0,
                                                  const int* __restrict__ outcnt,
                                                  const float* __restrict__ gate_g,
                                                  const int* __restrict__ seg_ptr,
                                                  const int* __restrict__ epay,
                                                  unsigned* __restrict__ g_out_bf,
                                                  float* __restrict__ g_out_f32,
                                                  int N, int last) {
    __shared__ float gateL[8];
    if (threadIdx.x < 8) gateL[threadIdx.x] = gate_g[threadIdx.x];
    __syncthreads();
    int hw = threadIdx.x >> 5;       // 0..7
    int lane = threadIdx.x & 31;
    int ng0 = blockIdx.x * 32 + hw * 4;
    if (ng0 >= N) return;            // N%4==0 so ng0+4 <= N always
    const uint2* gp = (const uint2*)g_in;

    float a[4][4];
#pragma unroll
    for (int g = 0; g < 4; g++)
#pragma unroll
        for (int i = 0; i < 4; i++) a[g][i] = 0.0f;
    int deg[4] = {0, 0, 0, 0};

    for (int b = 0; b < NB; b++) {
        int idx = b * N + ng0 + (lane < 5 ? lane : 4);
        int rp = seg_ptr[idx];
        int B0 = __shfl(rp, 0, 32), B1 = __shfl(rp, 1, 32), B2 = __shfl(rp, 2, 32);
        int B3 = __shfl(rp, 3, 32), B4 = __shfl(rp, 4, 32);
        deg[0] += B1 - B0; deg[1] += B2 - B1; deg[2] += B3 - B2; deg[3] += B4 - B3;
        for (int base = B0; base < B4; base += 32) {
            int n = B4 - base; if (n > 32) n = 32;
            int pay = 0;
            if (lane < n) pay = epay[base + lane];
            int j = 0;
            for (; j + 8 <= n; j += 8) {
                int pj[8];
#pragma unroll
                for (int u = 0; u < 8; u++) pj[u] = __shfl(pay, j + u, 32);
                uint2 v[8];
#pragma unroll
                for (int u = 0; u < 8; u++)
                    v[u] = gp[(size_t)(pj[u] & 0xFFFF) * 32 + lane];
#pragma unroll
                for (int u = 0; u < 8; u++) {
                    float c = gateL[(unsigned)pj[u] >> 16];
                    uint2 vv = v[u];
                    int pos = base + j + u;
                    int g = (pos >= B1) + (pos >= B2) + (pos >= B3);
                    switch (g) {
                        case 0: ACC(0); break;
                        case 1: ACC(1); break;
                        case 2: ACC(2); break;
                        default: ACC(3); break;
                    }
                }
            }
            for (; j < n; j++) {
                int pj = __shfl(pay, j, 32);
                float c = gateL[(unsigned)pj >> 16];
                uint2 vv = gp[(size_t)(pj & 0xFFFF) * 32 + lane];
                int pos = base + j;
                int g = (pos >= B1) + (pos >= B2) + (pos >= B3);
                switch (g) {
                    case 0: ACC(0); break;
                    case 1: ACC(1); break;
                    case 2: ACC(2); break;
                    default: ACC(3); break;
                }
            }
        }
    }

#pragma unroll
    for (int g = 0; g < 4; g++) {
        int node = ng0 + g;
        int ic = deg[g]; if (ic < 1) ic = 1;
        float dn = rsqrtf((float)ic) * (1.0f - ALPHA);
        float4 fv = *(const float4*)(feat0 + (size_t)node * DD + lane * 4);
        float h0 = dn * a[g][0] + ALPHA * fv.x;
        float h1 = dn * a[g][1] + ALPHA * fv.y;
        float h2 = dn * a[g][2] + ALPHA * fv.z;
        float h3 = dn * a[g][3] + ALPHA * fv.w;
        if (last) {
            float4 o = {h0, h1, h2, h3};
            *(float4*)(g_out_f32 + (size_t)node * DD + lane * 4) = o;
        } else {
            int oc = outcnt[node]; if (oc < 1) oc = 1;
            float sc = rsqrtf((float)oc);
            uint2 o;
            o.x = bf16rne(h0 * sc) | (bf16rne(h1 * sc) << 16);
            o.y = bf16rne(h2 * sc) | (bf16rne(h3 * sc) << 16);
            ((uint2*)g_out_bf)[(size_t)node * 32 + lane] = o;
        }
    }
}

// [N,128]@[128,128] GEMM, f32 vector ALU (no f32 MFMA on CDNA4).
__global__ __launch_bounds__(256) void mlp_kernel(const float* __restrict__ in,
                                                  const float* __restrict__ W,
                                                  const float* __restrict__ bias,
                                                  float* __restrict__ out, int N, int do_gelu) {
    __shared__ float ins[64 * DD];   // 32 KB
    __shared__ float Wt[64 * DD];    // 32 KB
    int tid = threadIdx.x;
    int row0 = blockIdx.x * 64;
    int nrows = N - row0; if (nrows > 64) nrows = 64;
    for (int i = tid; i < nrows * 32; i += 256)
        ((float4*)ins)[i] = ((const float4*)(in + (size_t)row0 * DD))[i];

    int jc = (tid & 31) * 4;
    int rg = (tid >> 5) * 8;
    float acc[8][4];
#pragma unroll
    for (int r = 0; r < 8; r++)
#pragma unroll
        for (int c = 0; c < 4; c++) acc[r][c] = 0.0f;

    for (int k0 = 0; k0 < DD; k0 += 64) {
        __syncthreads();
        for (int i = tid; i < 64 * 32; i += 256)
            ((float4*)Wt)[i] = ((const float4*)(W + (size_t)k0 * DD))[i];
        __syncthreads();
#pragma unroll 2
        for (int k = 0; k < 64; k += 4) {
            float4 wv[4];
#pragma unroll
            for (int i = 0; i < 4; i++) wv[i] = *(const float4*)&Wt[(k + i) * DD + jc];
#pragma unroll
            for (int r = 0; r < 8; r++) {
                float4 a = *(const float4*)&ins[(rg + r) * DD + k0 + k];
                acc[r][0] += a.x * wv[0].x + a.y * wv[1].x + a.z * wv[2].x + a.w * wv[3].x;
                acc[r][1] += a.x * wv[0].y + a.y * wv[1].y + a.z * wv[2].y + a.w * wv[3].y;
                acc[r][2] += a.x * wv[0].z + a.y * wv[1].z + a.z * wv[2].z + a.w * wv[3].z;
                acc[r][3] += a.x * wv[0].w + a.y * wv[1].w + a.z * wv[2].w + a.w * wv[3].w;
            }
        }
    }
    float4 bv = *(const float4*)&bias[jc];
#pragma unroll
    for (int r = 0; r < 8; r++) {
        int row = row0 + rg + r;
        if (row >= N) continue;
        float4 v;
        v.x = acc[r][0] + bv.x; v.y = acc[r][1] + bv.y;
        v.z = acc[r][2] + bv.z; v.w = acc[r][3] + bv.w;
        if (do_gelu) {
            v.x = 0.5f * v.x * (1.0f + erff(v.x * 0.70710678118654752f));
            v.y = 0.5f * v.y * (1.0f + erff(v.y * 0.70710678118654752f));
            v.z = 0.5f * v.z * (1.0f + erff(v.z * 0.70710678118654752f));
            v.w = 0.5f * v.w * (1.0f + erff(v.w * 0.70710678118654752f));
        }
        *(float4*)(out + (size_t)row * DD + jc) = v;
    }
}

extern "C" void kernel_launch(void* const* d_in, const int* in_sizes, int n_in,
                              void* d_out, int out_size, void* d_ws, size_t ws_size,
                              hipStream_t stream) {
    const float* feat = (const float*)d_in[0];
    const int*   e_feat = (const int*)d_in[1];
    const int*   src = (const int*)d_in[2];
    const int*   dst = (const int*)d_in[3];
    const float* emb = (const float*)d_in[4];
    const float* We1 = (const float*)d_in[5];
    const float* be1 = (const float*)d_in[6];
    const float* We2 = (const float*)d_in[7];
    const float* be2 = (const float*)d_in[8];
    const float* W1  = (const float*)d_in[9];
    const float* b1  = (const float*)d_in[10];
    const float* W2  = (const float*)d_in[11];
    const float* b2  = (const float*)d_in[12];
    float* out = (float*)d_out;

    const int N = NNODES, E = NEDGES;
    const int M = NB * N;                 // 350000 (bucket,dst) bins
    char* ws = (char*)d_ws;
    size_t off = 0;
    unsigned* ga = (unsigned*)(ws + off);  off += (size_t)N * 256;      // 12.8 MB bf16 state
    unsigned* gb = (unsigned*)(ws + off);  off += (size_t)N * 256;      // 12.8 MB bf16 state
    float* hfin = (float*)(ws + off);      off += (size_t)N * DD * 4;   // 25.6 MB f32 final h
    int*   epay = (int*)(ws + off);        off += (size_t)E * 4;        // 6.4 MB
    int*   seg_ptr = (int*)(ws + off);     off += (size_t)(M + 1) * 4;  // 1.4 MB
    int*   zbase = (int*)(ws + off);       off += (size_t)(2 * M + N) * 4; // cnt4|cursor|outcnt
    float* gate = (float*)(ws + off);      off += 64;
    int* cnt4   = zbase;
    int* cursor = zbase + M;
    int* outcnt = zbase + 2 * M;
    float* hidden = (float*)ws;   // aliases ga+gb (25.6 MB), free after hops

    hipMemsetAsync(zbase, 0, (size_t)(2 * M + N) * 4, stream);
    gate_kernel<<<1, 64, 0, stream>>>(emb, We1, be1, We2, be2, gate);
    deg_kernel<<<E / 256, 256, 0, stream>>>(src, dst, cnt4, E);
    scan_kernel<<<1, 1024, 0, stream>>>(cnt4, seg_ptr, M, E);
    scatter_kernel<<<E / 256, 256, 0, stream>>>(src, dst, e_feat, seg_ptr,
                                                cursor, outcnt, epay, E);
    scale_kernel<<<(N * 32 + 255) / 256, 256, 0, stream>>>(feat, outcnt, ga, N);

    const unsigned* gin = ga;
    unsigned* gout = gb;
    for (int k = 0; k < KHOPS; k++) {
        int last = (k == KHOPS - 1);
        hop_kernel<<<(N + 31) / 32, 256, 0, stream>>>(gin, feat, outcnt, gate, seg_ptr,
                                                      epay, gout, hfin, N, last);
        gin = gout;
        gout = (gout == ga) ? gb : ga;
    }
    // hfin = final h (f32 row-major); hidden aliases the bf16 buffers.
    mlp_kernel<<<(N + 63) / 64, 256, 0, stream>>>(hfin, W1, b1, hidden, N, 1);
    mlp_kernel<<<(N + 63) / 64, 256, 0, stream>>>(hidden, W2, b2, out, N, 0);
}

// Round 7
// 957.823 us; speedup vs baseline: 2.1161x; 2.1161x over previous
//
#include <hip/hip_runtime.h>
#include <cmath>

// PropConv: K=10 hop gated propagation on a fixed graph + output MLP.
// R7: revert R6 bucketing (no cross-block phase coherence -> L2 thesis dead;
// hops pinned at ~7TB/s L3 ceiling with bf16 state, accepted). Fix the two
// non-hop sinks instead: (1) 81us single-block serial scan -> 3-kernel
// multi-block scan (~8us); (2) ~140us f32 vector-ALU MLP -> bf16 MFMA
// (16x16x32) with W transposed+converted in LDS, hidden kept bf16 (~10us).

#define NNODES 50000
#define NEDGES 1600000
#define DD 128
#define KHOPS 10
#define ALPHA 0.1f

typedef short short8 __attribute__((ext_vector_type(8)));
typedef float f32x4 __attribute__((ext_vector_type(4)));

static __device__ __forceinline__ unsigned bf16rne(float x) {
    unsigned u = __float_as_uint(x);
    return (u + 0x7FFFu + ((u >> 16) & 1u)) >> 16;
}
static __device__ __forceinline__ float bf_lo(unsigned w) { return __uint_as_float(w << 16); }
static __device__ __forceinline__ float bf_hi(unsigned w) { return __uint_as_float(w & 0xFFFF0000u); }

// 8-entry gate table: gate MLP has only 8 distinct inputs (etypes).
__global__ void gate_kernel(const float* __restrict__ emb, const float* __restrict__ We1,
                            const float* __restrict__ be1, const float* __restrict__ We2,
                            const float* __restrict__ be2, float* __restrict__ gate) {
    int t = threadIdx.x;
    if (t >= 8) return;
    float acc2 = 0.0f;
    for (int j = 0; j < 32; j++) {
        float a = be1[j];
        for (int k = 0; k < DD; k++) a += emb[t * DD + k] * We1[k * 32 + j];
        float g = 0.5f * a * (1.0f + erff(a * 0.70710678118654752f));  // exact GELU
        acc2 += g * We2[j];
    }
    acc2 += be2[0];
    gate[t] = 1.0f + 1.0f / (1.0f + expf(-acc2));   // 1 + sigmoid
}

__global__ void deg_in_kernel(const int* __restrict__ dst, int* __restrict__ incnt, int E) {
    int e = blockIdx.x * blockDim.x + threadIdx.x;
    if (e < E) atomicAdd(&incnt[dst[e]], 1);
}

// ---- 3-kernel multi-block exclusive scan of incnt -> row_ptr ----
__global__ __launch_bounds__(256) void scan1_kernel(const int* __restrict__ cnt,
                                                    int* __restrict__ excl,
                                                    int* __restrict__ bsum, int N) {
    __shared__ int sh[256];
    int t = threadIdx.x;
    int g = blockIdx.x * 256 + t;
    int v = (g < N) ? cnt[g] : 0;
    sh[t] = v;
    __syncthreads();
    for (int off = 1; off < 256; off <<= 1) {
        int u = 0;
        if (t >= off) u = sh[t - off];
        __syncthreads();
        sh[t] += u;
        __syncthreads();
    }
    if (g < N) excl[g] = sh[t] - v;          // exclusive within block
    if (t == 255) bsum[blockIdx.x] = sh[255];
}
__global__ __launch_bounds__(256) void scan2_kernel(int* __restrict__ bsum, int nb) {
    __shared__ int sh[256];
    int t = threadIdx.x;
    int v = (t < nb) ? bsum[t] : 0;
    sh[t] = v;
    __syncthreads();
    for (int off = 1; off < 256; off <<= 1) {
        int u = 0;
        if (t >= off) u = sh[t - off];
        __syncthreads();
        sh[t] += u;
        __syncthreads();
    }
    if (t < nb) bsum[t] = sh[t] - v;         // exclusive
}
__global__ __launch_bounds__(256) void scan3_kernel(const int* __restrict__ excl,
                                                    const int* __restrict__ bsum,
                                                    int* __restrict__ row_ptr, int N, int E) {
    int g = blockIdx.x * 256 + threadIdx.x;
    if (g < N) row_ptr[g] = excl[g] + bsum[g >> 8];
    if (g == N) row_ptr[N] = E;
}

// Bucket edges by dst. 4B payload: src (16b) | etype (<<16). Also builds outcnt.
__global__ void scatter_kernel(const int* __restrict__ src, const int* __restrict__ dst,
                               const int* __restrict__ ef, const int* __restrict__ row_ptr,
                               int* __restrict__ cursor, int* __restrict__ outcnt,
                               int* __restrict__ epay, int E) {
    int e = blockIdx.x * blockDim.x + threadIdx.x;
    if (e >= E) return;
    int d = dst[e];
    int s = src[e];
    int pos = row_ptr[d] + atomicAdd(&cursor[d], 1);
    epay[pos] = s | (ef[e] << 16);
    atomicAdd(&outcnt[s], 1);
}

// g0 = bf16(feat * src_norm), row-major [N][128] bf16 (256B rows).
__global__ void scale_kernel(const float* __restrict__ feat, const int* __restrict__ outcnt,
                             unsigned* __restrict__ g0, int N) {
    int i = blockIdx.x * blockDim.x + threadIdx.x;   // one float4-group (4 cols)
    if (i >= N * 32) return;
    int row = i >> 5;
    int oc = outcnt[row]; if (oc < 1) oc = 1;
    float sn = rsqrtf((float)oc);
    float4 v = ((const float4*)feat)[i];
    uint2 o;
    o.x = bf16rne(v.x * sn) | (bf16rne(v.y * sn) << 16);
    o.y = bf16rne(v.z * sn) | (bf16rne(v.w * sn) << 16);
    ((uint2*)g0)[i] = o;
}

// Half-wave (32 lanes) per dst node; lane holds uint2 = 4 bf16 cols of the
// 256B row. Payloads loaded coalesced in chunks of 32, broadcast via __shfl;
// x8 unroll -> 8 independent 8B gathers in flight per lane. Epilogue in f32:
// h = .9*dstn*agg + .1*feat0; stores bf16(h*srcn); last hop stores bf16(h).
__global__ __launch_bounds__(256) void hop_kernel(const unsigned* __restrict__ g_in,
                                                  const float* __restrict__ feat0,
                                                  const int* __restrict__ incnt,
                                                  const int* __restrict__ outcnt,
                                                  const float* __restrict__ gate_g,
                                                  const int* __restrict__ row_ptr,
                                                  const int* __restrict__ epay,
                                                  unsigned* __restrict__ g_out,
                                                  int N, int last) {
    __shared__ float gateL[8];
    if (threadIdx.x < 8) gateL[threadIdx.x] = gate_g[threadIdx.x];
    __syncthreads();
    int half = threadIdx.x >> 5;     // 0..7
    int lane = threadIdx.x & 31;
    int node = blockIdx.x * 8 + half;
    if (node >= N) return;
    int beg = row_ptr[node], end = row_ptr[node + 1];
    const uint2* gp = (const uint2*)g_in;            // row = 32 uint2
    float a0 = 0.f, a1 = 0.f, a2 = 0.f, a3 = 0.f;
    for (int base = beg; base < end; base += 32) {
        int n = end - base; if (n > 32) n = 32;
        int p = 0;
        if (lane < n) p = epay[base + lane];
        int j = 0;
        for (; j + 8 <= n; j += 8) {
            int pj[8];
#pragma unroll
            for (int u = 0; u < 8; u++) pj[u] = __shfl(p, j + u, 32);
            uint2 v[8];
#pragma unroll
            for (int u = 0; u < 8; u++)
                v[u] = gp[(size_t)(pj[u] & 0xFFFF) * 32 + lane];
#pragma unroll
            for (int u = 0; u < 8; u++) {
                float c = gateL[(unsigned)pj[u] >> 16];
                a0 += c * bf_lo(v[u].x); a1 += c * bf_hi(v[u].x);
                a2 += c * bf_lo(v[u].y); a3 += c * bf_hi(v[u].y);
            }
        }
        for (; j < n; j++) {
            int pj = __shfl(p, j, 32);
            float c = gateL[(unsigned)pj >> 16];
            uint2 v = gp[(size_t)(pj & 0xFFFF) * 32 + lane];
            a0 += c * bf_lo(v.x); a1 += c * bf_hi(v.x);
            a2 += c * bf_lo(v.y); a3 += c * bf_hi(v.y);
        }
    }
    int ic = incnt[node]; if (ic < 1) ic = 1;
    float dn = rsqrtf((float)ic) * (1.0f - ALPHA);
    float4 fv = *(const float4*)(feat0 + (size_t)node * DD + lane * 4);
    float h0 = dn * a0 + ALPHA * fv.x;
    float h1 = dn * a1 + ALPHA * fv.y;
    float h2 = dn * a2 + ALPHA * fv.z;
    float h3 = dn * a3 + ALPHA * fv.w;
    float sc = 1.0f;
    if (!last) { int oc = outcnt[node]; if (oc < 1) oc = 1; sc = rsqrtf((float)oc); }
    uint2 o;
    o.x = bf16rne(h0 * sc) | (bf16rne(h1 * sc) << 16);
    o.y = bf16rne(h2 * sc) | (bf16rne(h3 * sc) << 16);
    ((uint2*)g_out)[(size_t)node * 32 + lane] = o;
}

// bf16 MFMA MLP layer: out[N,128] = act(in[N,128] @ W[128,128] + b).
// Block = 256 thr (4 waves), 64-row tile, full K=128 and all 128 cols.
// A staged bf16 in LDS (stride 136 for bank spread); W transposed+converted
// f32->bf16 into LDS as Bs[n][k]. Verified gfx950 layouts:
//   A[m=lane&15][k=quad*8+j], B[k=quad*8+j][n=lane&15],
//   D col=lane&15, row=quad*4+reg.
#define ASTR 136
__global__ __launch_bounds__(256) void mlp_mfma_kernel(const unsigned short* __restrict__ in,
                                                       const float* __restrict__ W,
                                                       const float* __restrict__ bias,
                                                       void* __restrict__ outp,
                                                       int N, int mode) {  // mode0: gelu+bf16 out; mode1: f32 out
    __shared__ unsigned short As[64 * ASTR];    // 17.4 KB
    __shared__ unsigned short Bs[128 * ASTR];   // 34.8 KB
    int tid = threadIdx.x;
    int row0 = blockIdx.x * 64;
    // stage A: 64 rows x 128 bf16 (clamp rows >= N)
    for (int i = tid; i < 64 * 16; i += 256) {
        int r = i >> 4, c8 = i & 15;
        int gr = row0 + r; if (gr >= N) gr = N - 1;
        uint4 v = *(const uint4*)(in + (size_t)gr * DD + c8 * 8);
        *(uint4*)&As[r * ASTR + c8 * 8] = v;
    }
    // stage B transposed: Bs[n][k] = bf16(W[k][n])
    for (int i = tid; i < 128 * 128; i += 256) {
        int k = i >> 7, n = i & 127;
        Bs[n * ASTR + k] = (unsigned short)bf16rne(W[i]);
    }
    __syncthreads();

    int wv = tid >> 6, lane = tid & 63;
    int m = lane & 15, quad = lane >> 4;
    const unsigned short* arow = &As[(16 * wv + m) * ASTR + quad * 8];
    f32x4 acc[8];
#pragma unroll
    for (int t = 0; t < 8; t++) {
        const unsigned short* brow = &Bs[(t * 16 + m) * ASTR + quad * 8];
        f32x4 c = {0.f, 0.f, 0.f, 0.f};
#pragma unroll
        for (int s = 0; s < 4; s++) {
            short8 a = *(const short8*)(arow + s * 32);
            short8 b = *(const short8*)(brow + s * 32);
            c = __builtin_amdgcn_mfma_f32_16x16x32_bf16(a, b, c, 0, 0, 0);
        }
        acc[t] = c;
    }
#pragma unroll
    for (int t = 0; t < 8; t++) {
        float bv = bias[t * 16 + m];
#pragma unroll
        for (int r = 0; r < 4; r++) {
            int grow = row0 + 16 * wv + quad * 4 + r;
            if (grow >= N) continue;
            float v = acc[t][r] + bv;
            size_t oidx = (size_t)grow * DD + t * 16 + m;
            if (mode == 0) {
                v = 0.5f * v * (1.0f + erff(v * 0.70710678118654752f));
                ((unsigned short*)outp)[oidx] = (unsigned short)bf16rne(v);
            } else {
                ((float*)outp)[oidx] = v;
            }
        }
    }
}

extern "C" void kernel_launch(void* const* d_in, const int* in_sizes, int n_in,
                              void* d_out, int out_size, void* d_ws, size_t ws_size,
                              hipStream_t stream) {
    const float* feat = (const float*)d_in[0];
    const int*   e_feat = (const int*)d_in[1];
    const int*   src = (const int*)d_in[2];
    const int*   dst = (const int*)d_in[3];
    const float* emb = (const float*)d_in[4];
    const float* We1 = (const float*)d_in[5];
    const float* be1 = (const float*)d_in[6];
    const float* We2 = (const float*)d_in[7];
    const float* be2 = (const float*)d_in[8];
    const float* W1  = (const float*)d_in[9];
    const float* b1  = (const float*)d_in[10];
    const float* W2  = (const float*)d_in[11];
    const float* b2  = (const float*)d_in[12];
    float* out = (float*)d_out;

    const int N = NNODES, E = NEDGES;
    const int NBLK = (N + 255) / 256;     // 196 scan blocks
    char* ws = (char*)d_ws;
    size_t off = 0;
    unsigned* ga = (unsigned*)(ws + off);  off += (size_t)N * 256;    // 12.8 MB bf16 state
    unsigned* gb = (unsigned*)(ws + off);  off += (size_t)N * 256;    // 12.8 MB bf16 state
    int*   epay = (int*)(ws + off);        off += (size_t)E * 4;      // 6.4 MB
    int*   row_ptr = (int*)(ws + off);     off += (size_t)(N + 1) * 4;
    int*   excl = (int*)(ws + off);        off += (size_t)N * 4;
    int*   bsum = (int*)(ws + off);        off += 256 * 4;
    int*   cnts = (int*)(ws + off);        off += (size_t)3 * N * 4;  // incnt|outcnt|cursor
    float* gate = (float*)(ws + off);      off += 64;
    int* incnt  = cnts;
    int* outcnt = cnts + N;
    int* cursor = cnts + 2 * N;

    hipMemsetAsync(cnts, 0, (size_t)3 * N * 4, stream);
    gate_kernel<<<1, 64, 0, stream>>>(emb, We1, be1, We2, be2, gate);
    deg_in_kernel<<<E / 256, 256, 0, stream>>>(dst, incnt, E);
    scan1_kernel<<<NBLK, 256, 0, stream>>>(incnt, excl, bsum, N);
    scan2_kernel<<<1, 256, 0, stream>>>(bsum, NBLK);
    scan3_kernel<<<(N + 256) / 256 + 1, 256, 0, stream>>>(excl, bsum, row_ptr, N, E);
    scatter_kernel<<<E / 256, 256, 0, stream>>>(src, dst, e_feat, row_ptr,
                                                cursor, outcnt, epay, E);
    scale_kernel<<<(N * 32 + 255) / 256, 256, 0, stream>>>(feat, outcnt, ga, N);

    const unsigned* gin = ga;
    unsigned* gout = gb;
    for (int k = 0; k < KHOPS; k++) {
        int last = (k == KHOPS - 1);
        hop_kernel<<<(N + 7) / 8, 256, 0, stream>>>(gin, feat, incnt, outcnt, gate,
                                                    row_ptr, epay, gout, N, last);
        gin = gout;
        gout = (gout == ga) ? gb : ga;
    }
    // Final h (unscaled, bf16) is in ga (hop9 writes ga); gb is free -> hidden.
    const unsigned short* hfin = (const unsigned short*)gin;
    unsigned short* hidden = (unsigned short*)gout;
    mlp_mfma_kernel<<<(N + 63) / 64, 256, 0, stream>>>(hfin, W1, b1, hidden, N, 0);
    mlp_mfma_kernel<<<(N + 63) / 64, 256, 0, stream>>>(hidden, W2, b2, out, N, 1);
}